// Round 11
// baseline (447.801 us; speedup 1.0000x reference)
//
#include <hip/hip_runtime.h>

// MoE combine: out[t] = sum_k w[t,k] * moe_output[mapped_slots[t,k]]
// w = scores / (sum_k scores + eps). T=8192, K=2, H=4096 fp32.
//
// Evidence log:
//  R4 vs R9: NT vs plain stores = 386.3 vs 384.9 us -> neutral.
//  R10: +1 warm diagnostic pass -> dur 442.7 => K_warm = 57.8 us.
//  Kernel absent from rocprof top-5 (~163us 1-GiB harness fills) => K < 160us.
//  dur_us = fixed harness restore/poison (~260-320us est.) + K_cold.
//
// R11 DIAGNOSTIC: pass 2 now gathers from the FIRST 256 MiB of d_ws
// (L3-cold: poison fill's L3 tail is its last ~256 MiB and pass 1 evicts
// the rest), writes to ws[512..640 MiB). dur_us - 384.9 = K_cold directly.
// Rule: <75 -> roofline; >=90 -> gather-locality optimization.

constexpr int HIDDEN   = 4096;
constexpr int N_TOKENS = 8192;
constexpr float EPS    = 1e-9f;

typedef float f32x4 __attribute__((ext_vector_type(4)));

__global__ __launch_bounds__(256) void moe_combine_kernel(
    const float* __restrict__ moe_output,   // [N_SLOTS, HIDDEN]
    const float* __restrict__ scores,       // [T, 2]
    const int*   __restrict__ mapped_slots, // [T, 2] (int32 on device)
    float*       __restrict__ out)          // [T, HIDDEN]
{
    const int t = blockIdx.x;

    const float s0  = scores[t * 2 + 0];
    const float s1  = scores[t * 2 + 1];
    const float inv = 1.0f / (s0 + s1 + EPS);
    const float w0  = s0 * inv;
    const float w1  = s1 * inv;

    const long long slot0 = (long long)mapped_slots[t * 2 + 0];
    const long long slot1 = (long long)mapped_slots[t * 2 + 1];

    const f32x4* __restrict__ a0 =
        reinterpret_cast<const f32x4*>(moe_output + slot0 * HIDDEN);
    const f32x4* __restrict__ a1 =
        reinterpret_cast<const f32x4*>(moe_output + slot1 * HIDDEN);
    f32x4* __restrict__ o =
        reinterpret_cast<f32x4*>(out + (long long)t * HIDDEN);

    #pragma unroll
    for (int i = threadIdx.x; i < HIDDEN / 4; i += 256) {
        const f32x4 v0 = a0[i];
        const f32x4 v1 = a1[i];
        o[i] = w0 * v0 + w1 * v1;
    }
}

extern "C" void kernel_launch(void* const* d_in, const int* in_sizes, int n_in,
                              void* d_out, int out_size, void* d_ws, size_t ws_size,
                              hipStream_t stream) {
    const float* moe_output   = (const float*)d_in[0];
    const float* scores       = (const float*)d_in[1];
    const int*   mapped_slots = (const int*)d_in[2];
    // d_in[3] = expert_counts: unused by the reference computation.
    float* out = (float*)d_out;

    // Pass 1: the real output (validated by the harness). Cold caches.
    moe_combine_kernel<<<N_TOKENS, 256, 0, stream>>>(
        moe_output, scores, mapped_slots, out);

    // Pass 2 (COLD DIAGNOSTIC): identical gather pattern over the first
    // 256 MiB of d_ws (cold at this point), writing to ws[512..640 MiB).
    // Idempotent, same work every call, graph-capture-safe.
    // Needs ws >= 640 MiB; ws_size is constant across calls, so this
    // branch is launch-invariant.
    if (ws_size >= (size_t)640 * 1024 * 1024) {
        const float* diag_src = (const float*)d_ws;              // [0, 256 MiB)
        float* diag_dst = (float*)d_ws + (size_t)128 * 1024 * 1024; // 512 MiB offset in floats
        moe_combine_kernel<<<N_TOKENS, 256, 0, stream>>>(
            diag_src, scores, mapped_slots, diag_dst);
    }
}